// Round 5
// baseline (23839.388 us; speedup 1.0000x reference)
//
#include <hip/hip_runtime.h>

#define NN 10368
#define EE 207360
#define TT 16

// ---- workspace layout (float offsets) ---- total ~6.1M floats = 24.4 MB
#define O_W0AT    0
#define O_W0BT    9216
#define O_WHHT    18432
#define O_WIHXT   55296
#define O_WCOMBT  92160
#define O_GB      129024
#define O_LOSS    129408
#define O_H       129424
#define O_C       (O_H  + NN*96)
#define O_A       (O_C  + NN*96)
#define O_BV      (O_A  + NN*96)
#define O_S2      (O_BV + NN*96)
#define O_X       (O_S2 + NN*96)

__device__ __forceinline__ float sigm(float x){ return 1.f/(1.f + expf(-x)); }

// ---------- prep: weight transposes + loss zero ----------
__global__ void k_convert(float* ws, const float* msgW0, const float* Whh, const float* Wih)
{
  int i = blockIdx.x*256 + threadIdx.x;
  if (i < 9216){ int k=i/96, j=i%96; ws[O_W0AT+i] = msgW0[j*192+k];    return; } i -= 9216;
  if (i < 9216){ int k=i/96, j=i%96; ws[O_W0BT+i] = msgW0[j*192+96+k]; return; } i -= 9216;
  if (i < 36864){ int k=i/384, j=i%384; ws[O_WHHT+i]  = Whh[j*96+k];   return; } i -= 36864;
  if (i < 36864){ int k=i/384, j=i%384; ws[O_WIHXT+i] = Wih[j*192+k];  return; } i -= 36864;
  if (i == 0){ ws[O_LOSS] = 0.f; }
}

// ---------- Wcomb = W_ih[:,96:] @ msg_W[2]  (fold last msg layer into gates) ----------
__global__ void k_wcomb(float* ws, const float* Wih, const float* msgW, const float* msgb)
{
  int t = blockIdx.x*256 + threadIdx.x;
  if (t >= 36864) return;
  int j = t % 384, qq = t / 384;
  float a0=0.f,a1=0.f,a2=0.f,a3=0.f;
  for (int r=0;r<96;r+=4){
    a0 = fmaf(Wih[j*192+96+r  ], msgW[2*9216+(r  )*96+qq], a0);
    a1 = fmaf(Wih[j*192+96+r+1], msgW[2*9216+(r+1)*96+qq], a1);
    a2 = fmaf(Wih[j*192+96+r+2], msgW[2*9216+(r+2)*96+qq], a2);
    a3 = fmaf(Wih[j*192+96+r+3], msgW[2*9216+(r+3)*96+qq], a3);
  }
  ws[O_WCOMBT + qq*384 + j] = (a0+a1)+(a2+a3);
  if (qq == 0){ // gate bias fold: 20 * W_ihm @ msg_b[3]
    float g=0.f;
    for (int r=0;r<96;r++) g = fmaf(Wih[j*192+96+r], msgb[288+r], g);
    ws[O_GB + j] = 20.f * g;
  }
}

// ---------- input MLP: x = h0 = mlp4(cat(embeds)); c = 0 ----------
__global__ __launch_bounds__(64) void k_input(float* ws,
    const int* q, const int* row, const int* col,
    const float* demb, const float* remb, const float* cemb,
    const float* inW0, const float* inW, const float* inb)
{
  __shared__ float scr[96*65];
  int tid = threadIdx.x;
  int n = blockIdx.x*64 + tid;
  int qv=q[n], rv=row[n], cv=col[n];
  float in48[48];
  #pragma unroll
  for (int i=0;i<16;i++){
    in48[i]    = demb[qv*16+i];
    in48[16+i] = remb[rv*16+i];
    in48[32+i] = cemb[cv*16+i];
  }
  #pragma unroll 2
  for (int j=0;j<96;j++){
    float a0=inb[j], a1=0.f, a2=0.f, a3=0.f;
    #pragma unroll
    for (int k=0;k<48;k+=4){
      a0=fmaf(inW0[j*48+k  ],in48[k  ],a0); a1=fmaf(inW0[j*48+k+1],in48[k+1],a1);
      a2=fmaf(inW0[j*48+k+2],in48[k+2],a2); a3=fmaf(inW0[j*48+k+3],in48[k+3],a3);
    }
    scr[j*65+tid] = fmaxf((a0+a1)+(a2+a3), 0.f);
  }
  float v[96];
  #pragma unroll
  for (int k=0;k<96;k++) v[k] = scr[k*65+tid];

  for (int l=0;l<2;l++){
    const float* W = inW + l*9216;
    const float* b = inb + (l+1)*96;
    #pragma unroll 2
    for (int j=0;j<96;j++){
      float a0=b[j], a1=0.f, a2=0.f, a3=0.f;
      #pragma unroll
      for (int k=0;k<96;k+=4){
        a0=fmaf(W[j*96+k  ],v[k  ],a0); a1=fmaf(W[j*96+k+1],v[k+1],a1);
        a2=fmaf(W[j*96+k+2],v[k+2],a2); a3=fmaf(W[j*96+k+3],v[k+3],a3);
      }
      scr[j*65+tid] = fmaxf((a0+a1)+(a2+a3), 0.f);
    }
    #pragma unroll
    for (int k=0;k<96;k++) v[k] = scr[k*65+tid];
  }
  { // final layer, no relu
    const float* W = inW + 2*9216;
    const float* b = inb + 3*96;
    #pragma unroll 2
    for (int j=0;j<96;j++){
      float a0=b[j], a1=0.f, a2=0.f, a3=0.f;
      #pragma unroll
      for (int k=0;k<96;k+=4){
        a0=fmaf(W[j*96+k  ],v[k  ],a0); a1=fmaf(W[j*96+k+1],v[k+1],a1);
        a2=fmaf(W[j*96+k+2],v[k+2],a2); a3=fmaf(W[j*96+k+3],v[k+3],a3);
      }
      scr[j*65+tid] = (a0+a1)+(a2+a3);
    }
  }
  __syncthreads();
  float* h = ws + O_H; float* c = ws + O_C; float* x = ws + O_X;
  int nb = blockIdx.x*64;
  for (int idx=tid; idx<64*96; idx+=64){
    int nl = idx/96, j = idx%96;
    float vv = scr[j*65 + nl];
    h[(nb+nl)*96 + j] = vv;
    x[(nb+nl)*96 + j] = vv;
    c[(nb+nl)*96 + j] = 0.f;
  }
}

// ---------- one-time: A/B for step 0 from h0 ----------
__global__ __launch_bounds__(192) void k_ab0(float* ws, const float* msgb)
{
  int tid = threadIdx.x; int g = tid/96, j = tid%96;
  int nq = blockIdx.x*2 + g; int n0 = nq*8;
  const float* h  = ws + O_H;
  const float* WA = ws + O_W0AT;
  const float* WB = ws + O_W0BT;
  float aa[8],ab[8];
  #pragma unroll
  for (int i=0;i<8;i++){ aa[i]=0.f; ab[i]=0.f; }
  #pragma unroll 2
  for (int k=0;k<96;k++){
    float wa=WA[k*96+j],  wb=WB[k*96+j];
    #pragma unroll
    for (int i=0;i<8;i++){
      float xv = h[(n0+i)*96+k];
      aa[i]=fmaf(wa,xv,aa[i]); ab[i]=fmaf(wb,xv,ab[i]);
    }
  }
  float* A=ws+O_A; float* Bv=ws+O_BV;
  float b0v = msgb[j];
  #pragma unroll
  for (int i=0;i<8;i++){
    int n=n0+i;
    A[n*96+j]=aa[i]; Bv[n*96+j]=ab[i]+b0v;
  }
}

// ---------- per-step edge MLP + aggregation ----------
// s2[n] = sum_{v in nbr(n)} relu(W2 relu(W1 relu(A[v]+B[n])))
// LDS halved vs r4: stage 48-feature chunks (own-column RW needs no sync);
// syncs only around the cross-column 20-edge reductions.
__global__ __launch_bounds__(128, 3) void k_edge(float* ws, const int* dst,
                                                 const float* msgW, const float* msgb)
{
  __shared__ float scr[48*129];          // 24.8 KB -> 6 blocks/CU (was 49.7 KB -> 3)
  int tid = threadIdx.x;
  int nb = blockIdx.x*6;                 // 6 nodes, 120 edges per block
  int e = nb*20 + tid; if (e >= EE) e = EE-1;
  int v = dst[e];
  int ln = tid/20; if (ln > 5) ln = 5;
  int n = nb + ln;

  const float* A  = ws + O_A;
  const float* Bv = ws + O_BV;
  float vin[96];
  const float4* A4 = (const float4*)(A  + v*96);
  const float4* B4 = (const float4*)(Bv + n*96);
  #pragma unroll
  for (int kk=0;kk<24;kk++){
    float4 a = A4[kk], b = B4[kk];
    vin[kk*4+0]=fmaxf(a.x+b.x,0.f); vin[kk*4+1]=fmaxf(a.y+b.y,0.f);
    vin[kk*4+2]=fmaxf(a.z+b.z,0.f); vin[kk*4+3]=fmaxf(a.w+b.w,0.f);
  }
  const float* W1 = msgW;          const float* b1 = msgb + 96;
  // layer1 chunk A: j=0..47 -> LDS (own column)
  #pragma unroll 2
  for (int j=0;j<48;j++){
    float q0=b1[j], q1=0.f, q2=0.f, q3=0.f;
    #pragma unroll
    for (int k=0;k<96;k+=4){
      q0=fmaf(W1[j*96+k  ],vin[k  ],q0); q1=fmaf(W1[j*96+k+1],vin[k+1],q1);
      q2=fmaf(W1[j*96+k+2],vin[k+2],q2); q3=fmaf(W1[j*96+k+3],vin[k+3],q3);
    }
    scr[j*129+tid] = fmaxf((q0+q1)+(q2+q3), 0.f);
  }
  float hn[96];
  #pragma unroll
  for (int k=0;k<48;k++) hn[k] = scr[k*129+tid];   // self-reload chunk A
  // layer1 chunk B: j=48..95 (vin still live) -> same LDS rows
  #pragma unroll 2
  for (int j=48;j<96;j++){
    float q0=b1[j], q1=0.f, q2=0.f, q3=0.f;
    #pragma unroll
    for (int k=0;k<96;k+=4){
      q0=fmaf(W1[j*96+k  ],vin[k  ],q0); q1=fmaf(W1[j*96+k+1],vin[k+1],q1);
      q2=fmaf(W1[j*96+k+2],vin[k+2],q2); q3=fmaf(W1[j*96+k+3],vin[k+3],q3);
    }
    scr[(j-48)*129+tid] = fmaxf((q0+q1)+(q2+q3), 0.f);
  }
  #pragma unroll
  for (int k=48;k<96;k++) hn[k] = scr[(k-48)*129+tid];  // self-reload chunk B

  const float* W2 = msgW + 9216;   const float* b2 = msgb + 192;
  float* s2 = ws + O_S2;
  // layer2 chunk A: out rows 0..47
  #pragma unroll 2
  for (int j=0;j<48;j++){
    float q0=b2[j], q1=0.f, q2=0.f, q3=0.f;
    #pragma unroll
    for (int k=0;k<96;k+=4){
      q0=fmaf(W2[j*96+k  ],hn[k  ],q0); q1=fmaf(W2[j*96+k+1],hn[k+1],q1);
      q2=fmaf(W2[j*96+k+2],hn[k+2],q2); q3=fmaf(W2[j*96+k+3],hn[k+3],q3);
    }
    scr[j*129+tid] = fmaxf((q0+q1)+(q2+q3), 0.f);
  }
  __syncthreads();
  for (int idx=tid; idx<288; idx+=128){
    int node = idx/48, j = idx%48;
    const float* base = &scr[j*129 + node*20];
    float s=0.f;
    #pragma unroll
    for (int l=0;l<20;l++) s += base[l];
    s2[(nb+node)*96 + j] = s;
  }
  __syncthreads();
  // layer2 chunk B: out rows 48..95
  #pragma unroll 2
  for (int j=48;j<96;j++){
    float q0=b2[j], q1=0.f, q2=0.f, q3=0.f;
    #pragma unroll
    for (int k=0;k<96;k+=4){
      q0=fmaf(W2[j*96+k  ],hn[k  ],q0); q1=fmaf(W2[j*96+k+1],hn[k+1],q1);
      q2=fmaf(W2[j*96+k+2],hn[k+2],q2); q3=fmaf(W2[j*96+k+3],hn[k+3],q3);
    }
    scr[(j-48)*129+tid] = fmaxf((q0+q1)+(q2+q3), 0.f);
  }
  __syncthreads();
  for (int idx=tid; idx<288; idx+=128){
    int node = idx/48, j = idx%48;
    const float* base = &scr[j*129 + node*20];
    float s=0.f;
    #pragma unroll
    for (int l=0;l<20;l++) s += base[l];
    s2[(nb+node)*96 + 48 + j] = s;
  }
}

// ---------- per-step: LSTM gates + state + next A/B + logits/preds/loss ----------
__global__ __launch_bounds__(192) void k_lstm(float* ws, const int* labels,
                                              const float* msgb,
                                              const float* outW, const float* outb,
                                              float* out, int t)
{
  __shared__ float lh[16*97];
  __shared__ float lgt[160];
  int tid = threadIdx.x; int g = tid/96, j = tid%96;
  int nq = blockIdx.x*2 + g; int n0 = nq*8;
  const float* WX = ws + O_WIHXT;
  const float* WC = ws + O_WCOMBT;
  const float* WH = ws + O_WHHT;
  const float* s2 = ws + O_S2;
  const float* x  = ws + O_X;
  float* h = ws + O_H; float* c = ws + O_C;

  // reference scan carry: (h, rh, rc) init (x, 0, 0) — at t=0 the recurrent
  // term uses rh=0 (NOT h=x). hscale kills the W_hh term exactly at t=0.
  const float hscale = (t == 0) ? 0.f : 1.f;

  float a0[8],a1[8],a2[8],a3[8];
  {
    float gb0=ws[O_GB+j], gb1=ws[O_GB+96+j], gb2=ws[O_GB+192+j], gb3=ws[O_GB+288+j];
    #pragma unroll
    for (int i=0;i<8;i++){ a0[i]=gb0; a1[i]=gb1; a2[i]=gb2; a3[i]=gb3; }
  }
  // phase 1: frozen-input gate term  W_ihx @ x
  #pragma unroll 2
  for (int k=0;k<96;k++){
    float w0=WX[k*384+j], w1=WX[k*384+96+j], w2=WX[k*384+192+j], w3=WX[k*384+288+j];
    #pragma unroll
    for (int i=0;i<8;i++){
      float xv = x[(n0+i)*96+k];
      a0[i]=fmaf(w0,xv,a0[i]); a1[i]=fmaf(w1,xv,a1[i]);
      a2[i]=fmaf(w2,xv,a2[i]); a3[i]=fmaf(w3,xv,a3[i]);
    }
  }
  // phase 2: message (Wcomb@s2) + recurrent (Whh@rh), rh = (t==0 ? 0 : h)
  #pragma unroll 2
  for (int k=0;k<96;k++){
    float c0=WC[k*384+j], c1=WC[k*384+96+j], c2=WC[k*384+192+j], c3=WC[k*384+288+j];
    float h0=WH[k*384+j], h1=WH[k*384+96+j], h2=WH[k*384+192+j], h3=WH[k*384+288+j];
    #pragma unroll
    for (int i=0;i<8;i++){
      float sv = s2[(n0+i)*96+k];
      float rv = h [(n0+i)*96+k] * hscale;
      a0[i]=fmaf(c0,sv,fmaf(h0,rv,a0[i]));
      a1[i]=fmaf(c1,sv,fmaf(h1,rv,a1[i]));
      a2[i]=fmaf(c2,sv,fmaf(h2,rv,a2[i]));
      a3[i]=fmaf(c3,sv,fmaf(h3,rv,a3[i]));
    }
  }
  float nh[8], ncv[8];
  #pragma unroll
  for (int i=0;i<8;i++){
    int n=n0+i;
    float ig=sigm(a0[i]), fg=sigm(a1[i]), gg=tanhf(a2[i]), og=sigm(a3[i]);
    float cv = c[n*96+j];
    float nc = fg*cv + ig*gg;
    float nv = og*tanhf(nc);
    ncv[i]=nc; nh[i]=nv;
    lh[(g*8+i)*97 + j] = nv;
  }
  __syncthreads();   // all reads of old h done before rewrite
  #pragma unroll
  for (int i=0;i<8;i++){ int n=n0+i; c[n*96+j]=ncv[i]; h[n*96+j]=nh[i]; }

  // next-step A/B from fresh h (in LDS)
  const float* WA = ws + O_W0AT; const float* WB = ws + O_W0BT;
  float aa[8],ab[8];
  #pragma unroll
  for (int i=0;i<8;i++){ aa[i]=0.f; ab[i]=0.f; }
  #pragma unroll 2
  for (int k=0;k<96;k++){
    float wa=WA[k*96+j], wb=WB[k*96+j];
    #pragma unroll
    for (int i=0;i<8;i++){
      float hv = lh[(g*8+i)*97 + k];
      aa[i]=fmaf(wa,hv,aa[i]); ab[i]=fmaf(wb,hv,ab[i]);
    }
  }
  float* Aa=ws+O_A; float* Bb=ws+O_BV;
  float b0v = msgb[j];
  #pragma unroll
  for (int i=0;i<8;i++){ int n=n0+i; Aa[n*96+j]=aa[i]; Bb[n*96+j]=ab[i]+b0v; }

  // logits for this step
  if (j < 80){
    int ln = j/10, cls = j%10;
    int n = n0 + ln;
    float q0=outb[cls], q1=0.f, q2=0.f, q3=0.f;
    const float* hr = &lh[(g*8+ln)*97];
    #pragma unroll
    for (int k=0;k<96;k+=4){
      q0=fmaf(outW[cls*96+k  ],hr[k  ],q0); q1=fmaf(outW[cls*96+k+1],hr[k+1],q1);
      q2=fmaf(outW[cls*96+k+2],hr[k+2],q2); q3=fmaf(outW[cls*96+k+3],hr[k+3],q3);
    }
    float lg = (q0+q1)+(q2+q3);
    lgt[(g*8+ln)*10 + cls] = lg;
    out[165889 + (t*NN + n)*10 + cls] = lg;
  }
  __syncthreads();
  if (j < 8){
    int n = n0 + j;
    const float* L = &lgt[(g*8+j)*10];
    float m = L[0]; int bi = 0;
    #pragma unroll
    for (int cc=1;cc<10;cc++){ if (L[cc] > m){ m=L[cc]; bi=cc; } }
    float se = 0.f;
    #pragma unroll
    for (int cc=0;cc<10;cc++) se += expf(L[cc]-m);
    int lab = labels[n];
    float lp = L[lab] - m - logf(se);
    atomicAdd(ws + O_LOSS, -lp);
    out[t*NN + n] = (float)bi;
  }
}

__global__ void k_final(float* ws, float* out){
  if (threadIdx.x == 0 && blockIdx.x == 0)
    out[165888] = ws[O_LOSS] / (float)(TT*NN);
}

extern "C" void kernel_launch(void* const* d_in, const int* in_sizes, int n_in,
                              void* d_out, int out_size, void* d_ws, size_t ws_size,
                              hipStream_t stream)
{
  (void)in_sizes; (void)n_in; (void)out_size; (void)ws_size;
  const int* q      = (const int*)d_in[0];
  const int* row    = (const int*)d_in[1];
  const int* col    = (const int*)d_in[2];
  const int* labels = (const int*)d_in[3];
  // d_in[4] = src (implied by edge grouping: e in [20n,20n+20) has src==n)
  const int* dst    = (const int*)d_in[5];
  const float* demb  = (const float*)d_in[6];
  const float* remb  = (const float*)d_in[7];
  const float* cemb  = (const float*)d_in[8];
  const float* inW0  = (const float*)d_in[9];
  const float* inW   = (const float*)d_in[10];
  const float* inb   = (const float*)d_in[11];
  const float* msgW0 = (const float*)d_in[12];
  const float* msgW  = (const float*)d_in[13];
  const float* msgb  = (const float*)d_in[14];
  const float* Wih   = (const float*)d_in[15];
  const float* Whh   = (const float*)d_in[16];
  const float* outW  = (const float*)d_in[17];
  const float* outb  = (const float*)d_in[18];

  float* ws  = (float*)d_ws;
  float* out = (float*)d_out;

  hipLaunchKernelGGL(k_convert, dim3(361), dim3(256), 0, stream, ws, msgW0, Whh, Wih);
  hipLaunchKernelGGL(k_wcomb, dim3(144), dim3(256), 0, stream, ws, Wih, msgW, msgb);
  hipLaunchKernelGGL(k_input, dim3(162), dim3(64), 0, stream,
                     ws, q, row, col, demb, remb, cemb, inW0, inW, inb);
  hipLaunchKernelGGL(k_ab0, dim3(648), dim3(192), 0, stream, ws, msgb);
  for (int t=0; t<TT; ++t){
    hipLaunchKernelGGL(k_edge, dim3(1728), dim3(128), 0, stream, ws, dst, msgW, msgb);
    hipLaunchKernelGGL(k_lstm, dim3(648), dim3(192), 0, stream,
                       ws, labels, msgb, outW, outb, out, t);
  }
  hipLaunchKernelGGL(k_final, dim3(1), dim3(64), 0, stream, ws, out);
}

// Round 6
// 4104.050 us; speedup vs baseline: 5.8087x; 5.8087x over previous
//
#include <hip/hip_runtime.h>

#define NN 10368
#define EE 207360
#define TT 16

// ---- workspace layout (float offsets) ---- total ~6.13M floats = 24.5 MB
#define O_W0AT    0
#define O_W0BT    9216
#define O_WHHT    18432
#define O_WIHXT   55296
#define O_WCOMBT  92160
#define O_GB      129024
#define O_LOSS    129408
#define O_H       129424
#define O_C       (O_H  + NN*96)
#define O_A       (O_C  + NN*96)
#define O_BV      (O_A  + NN*96)
#define O_S2      (O_BV + NN*96)
#define O_X       (O_S2 + NN*96)
#define O_WFRAG   (O_X  + NN*96)   // ushort region: 2 layers x 3 levels x 18 tiles x 512 shorts

using bf16x8 = __attribute__((ext_vector_type(8))) short;
using f32x4  = __attribute__((ext_vector_type(4))) float;

__device__ __forceinline__ float sigm(float x){ return 1.f/(1.f + expf(-x)); }

__device__ __forceinline__ unsigned rne_bf16(float f){
  unsigned u = __float_as_uint(f);
  u += 0x7fffu + ((u >> 16) & 1u);
  return u >> 16;
}
__device__ __forceinline__ void split3(float x, short& h, short& m, short& l){
  unsigned uh = rne_bf16(x); h = (short)uh;
  float fh = __uint_as_float(uh << 16);
  float r1 = x - fh;
  unsigned um = rne_bf16(r1); m = (short)um;
  float fm = __uint_as_float(um << 16);
  float r2 = r1 - fm;
  l = (short)rne_bf16(r2);
}

// ---------- prep: weight transposes + loss zero ----------
__global__ void k_convert(float* ws, const float* msgW0, const float* Whh, const float* Wih)
{
  int i = blockIdx.x*256 + threadIdx.x;
  if (i < 9216){ int k=i/96, j=i%96; ws[O_W0AT+i] = msgW0[j*192+k];    return; } i -= 9216;
  if (i < 9216){ int k=i/96, j=i%96; ws[O_W0BT+i] = msgW0[j*192+96+k]; return; } i -= 9216;
  if (i < 36864){ int k=i/384, j=i%384; ws[O_WHHT+i]  = Whh[j*96+k];   return; } i -= 36864;
  if (i < 36864){ int k=i/384, j=i%384; ws[O_WIHXT+i] = Wih[j*192+k];  return; } i -= 36864;
  if (i == 0){ ws[O_LOSS] = 0.f; }
}

// ---------- msg W1/W2 -> bf16 split-3 B-fragments for mfma_f32_16x16x32_bf16 ----------
// frag element: B[k=quad*8+j][n=(lane&15)+16*nt] = W[n_out][k], k = 32*kt + quad*8 + j
// storage: wf[(((layer*3+lev)*18 + nt*3+kt)*64 + lane)*8 + j]
__global__ void k_wfrag(float* ws, const float* msgW)
{
  int idx = blockIdx.x*256 + threadIdx.x;
  if (idx >= 2*3*18*64) return;
  int lane = idx & 63;
  int tile = (idx >> 6) % 18;
  int lev  = (idx >> 6) / 18 % 3;
  int layer= (idx >> 6) / 54;
  int nt = tile/3, kt = tile%3;
  int nout = (lane & 15) + 16*nt;
  int q = lane >> 4;
  unsigned short* wf = (unsigned short*)(ws + O_WFRAG);
  unsigned short* dstp = wf + (size_t)(((layer*3+lev)*18 + tile)*64 + lane)*8;
  const float* W = msgW + layer*9216;
  for (int j=0;j<8;j++){
    float wv = W[nout*96 + 32*kt + 8*q + j];
    short h,m,l; split3(wv, h, m, l);
    dstp[j] = (unsigned short)(lev==0 ? h : (lev==1 ? m : l));
  }
}

// ---------- input MLP: x = h0 = mlp4(cat(embeds)); c = 0 ----------
__global__ __launch_bounds__(64) void k_input(float* ws,
    const int* q, const int* row, const int* col,
    const float* demb, const float* remb, const float* cemb,
    const float* inW0, const float* inW, const float* inb)
{
  __shared__ float scr[96*65];
  int tid = threadIdx.x;
  int n = blockIdx.x*64 + tid;
  int qv=q[n], rv=row[n], cv=col[n];
  float in48[48];
  #pragma unroll
  for (int i=0;i<16;i++){
    in48[i]    = demb[qv*16+i];
    in48[16+i] = remb[rv*16+i];
    in48[32+i] = cemb[cv*16+i];
  }
  #pragma unroll 2
  for (int j=0;j<96;j++){
    float a0=inb[j], a1=0.f, a2=0.f, a3=0.f;
    #pragma unroll
    for (int k=0;k<48;k+=4){
      a0=fmaf(inW0[j*48+k  ],in48[k  ],a0); a1=fmaf(inW0[j*48+k+1],in48[k+1],a1);
      a2=fmaf(inW0[j*48+k+2],in48[k+2],a2); a3=fmaf(inW0[j*48+k+3],in48[k+3],a3);
    }
    scr[j*65+tid] = fmaxf((a0+a1)+(a2+a3), 0.f);
  }
  float v[96];
  #pragma unroll
  for (int k=0;k<96;k++) v[k] = scr[k*65+tid];

  for (int l=0;l<2;l++){
    const float* W = inW + l*9216;
    const float* b = inb + (l+1)*96;
    #pragma unroll 2
    for (int j=0;j<96;j++){
      float a0=b[j], a1=0.f, a2=0.f, a3=0.f;
      #pragma unroll
      for (int k=0;k<96;k+=4){
        a0=fmaf(W[j*96+k  ],v[k  ],a0); a1=fmaf(W[j*96+k+1],v[k+1],a1);
        a2=fmaf(W[j*96+k+2],v[k+2],a2); a3=fmaf(W[j*96+k+3],v[k+3],a3);
      }
      scr[j*65+tid] = fmaxf((a0+a1)+(a2+a3), 0.f);
    }
    #pragma unroll
    for (int k=0;k<96;k++) v[k] = scr[k*65+tid];
  }
  { // final layer, no relu
    const float* W = inW + 2*9216;
    const float* b = inb + 3*96;
    #pragma unroll 2
    for (int j=0;j<96;j++){
      float a0=b[j], a1=0.f, a2=0.f, a3=0.f;
      #pragma unroll
      for (int k=0;k<96;k+=4){
        a0=fmaf(W[j*96+k  ],v[k  ],a0); a1=fmaf(W[j*96+k+1],v[k+1],a1);
        a2=fmaf(W[j*96+k+2],v[k+2],a2); a3=fmaf(W[j*96+k+3],v[k+3],a3);
      }
      scr[j*65+tid] = (a0+a1)+(a2+a3);
    }
  }
  __syncthreads();
  float* h = ws + O_H; float* c = ws + O_C; float* x = ws + O_X;
  int nb = blockIdx.x*64;
  for (int idx=tid; idx<64*96; idx+=64){
    int nl = idx/96, j = idx%96;
    float vv = scr[j*65 + nl];
    h[(nb+nl)*96 + j] = vv;
    x[(nb+nl)*96 + j] = vv;
    c[(nb+nl)*96 + j] = 0.f;
  }
}

// ---------- Wcomb = W_ih[:,96:] @ msg_W[2]  (fold last msg layer into gates) ----------
__global__ void k_wcomb(float* ws, const float* Wih, const float* msgW, const float* msgb)
{
  int t = blockIdx.x*256 + threadIdx.x;
  if (t >= 36864) return;
  int j = t % 384, qq = t / 384;
  float a0=0.f,a1=0.f,a2=0.f,a3=0.f;
  for (int r=0;r<96;r+=4){
    a0 = fmaf(Wih[j*192+96+r  ], msgW[2*9216+(r  )*96+qq], a0);
    a1 = fmaf(Wih[j*192+96+r+1], msgW[2*9216+(r+1)*96+qq], a1);
    a2 = fmaf(Wih[j*192+96+r+2], msgW[2*9216+(r+2)*96+qq], a2);
    a3 = fmaf(Wih[j*192+96+r+3], msgW[2*9216+(r+3)*96+qq], a3);
  }
  ws[O_WCOMBT + qq*384 + j] = (a0+a1)+(a2+a3);
  if (qq == 0){
    float g=0.f;
    for (int r=0;r<96;r++) g = fmaf(Wih[j*192+96+r], msgb[288+r], g);
    ws[O_GB + j] = 20.f * g;
  }
}

// ---------- one-time: A/B for step 0 from h0 ----------
__global__ __launch_bounds__(192) void k_ab0(float* ws, const float* msgb)
{
  int tid = threadIdx.x; int g = tid/96, j = tid%96;
  int nq = blockIdx.x*2 + g; int n0 = nq*8;
  const float* h  = ws + O_H;
  const float* WA = ws + O_W0AT;
  const float* WB = ws + O_W0BT;
  float aa[8],ab[8];
  #pragma unroll
  for (int i=0;i<8;i++){ aa[i]=0.f; ab[i]=0.f; }
  #pragma unroll 2
  for (int k=0;k<96;k++){
    float wa=WA[k*96+j],  wb=WB[k*96+j];
    #pragma unroll
    for (int i=0;i<8;i++){
      float xv = h[(n0+i)*96+k];
      aa[i]=fmaf(wa,xv,aa[i]); ab[i]=fmaf(wb,xv,ab[i]);
    }
  }
  float* A=ws+O_A; float* Bv=ws+O_BV;
  float b0v = msgb[j];
  #pragma unroll
  for (int i=0;i<8;i++){
    int n=n0+i;
    A[n*96+j]=aa[i]; Bv[n*96+j]=ab[i]+b0v;
  }
}

// ---------- per-step edge MLP via bf16 split-3 MFMA ----------
// block = 1 node (128 thr = 2 waves); wave w handles 16 slots (node padded 20->32).
// s2[n] = sum_{s<20} relu(W2 relu(W1 relu(A[dst[n*20+s]] + B[n]) + b1) + b2)
__global__ __launch_bounds__(128) void k_edge(float* ws, const int* dst, const float* msgb)
{
  __shared__ float tile[2][16*100];   // per-wave h1 relayout tile, 16 slots x 96 (+pad)
  __shared__ float part[2][96];
  int n = blockIdx.x;
  int w = threadIdx.x >> 6;
  int L = threadIdx.x & 63;
  int m = L & 15, q = L >> 4;
  int slot = 16*w + m;
  bool valid = slot < 20;
  int v = valid ? dst[n*20 + slot] : 0;

  const float* Aact = ws + O_A;
  const float* Bact = ws + O_BV;
  const unsigned short* wf = (const unsigned short*)(ws + O_WFRAG);

  // ---- build A-fragments of vin = relu(A[v]+B[n]) : layout A[m=lane&15][k=quad*8+j]
  bf16x8 aH[3], aM[3], aL[3];
  #pragma unroll
  for (int kt=0; kt<3; kt++){
    float r[8];
    if (valid){
      int k0 = 32*kt + 8*q;
      float4 a0 = *(const float4*)(Aact + (size_t)v*96 + k0);
      float4 a1 = *(const float4*)(Aact + (size_t)v*96 + k0 + 4);
      float4 b0 = *(const float4*)(Bact + (size_t)n*96 + k0);
      float4 b1 = *(const float4*)(Bact + (size_t)n*96 + k0 + 4);
      r[0]=fmaxf(a0.x+b0.x,0.f); r[1]=fmaxf(a0.y+b0.y,0.f);
      r[2]=fmaxf(a0.z+b0.z,0.f); r[3]=fmaxf(a0.w+b0.w,0.f);
      r[4]=fmaxf(a1.x+b1.x,0.f); r[5]=fmaxf(a1.y+b1.y,0.f);
      r[6]=fmaxf(a1.z+b1.z,0.f); r[7]=fmaxf(a1.w+b1.w,0.f);
    } else {
      #pragma unroll
      for (int j=0;j<8;j++) r[j]=0.f;
    }
    #pragma unroll
    for (int j=0;j<8;j++){
      short hh,mm,ll; split3(r[j], hh, mm, ll);
      aH[kt][j]=hh; aM[kt][j]=mm; aL[kt][j]=ll;
    }
  }

  // ---- GEMM1: h1 = relu(vin @ W1^T + b1) ; write into wave-private LDS tile
  #pragma unroll 2
  for (int nt=0; nt<6; nt++){
    f32x4 acc = {0.f,0.f,0.f,0.f};
    #pragma unroll
    for (int kt=0; kt<3; kt++){
      int tbase = (0*3+0)*18 + nt*3+kt;  // layer0, lev offsets applied below
      bf16x8 WH = ((const bf16x8*)wf)[(size_t)((0*3+0)*18 + nt*3+kt)*64 + L];
      bf16x8 WM = ((const bf16x8*)wf)[(size_t)((0*3+1)*18 + nt*3+kt)*64 + L];
      bf16x8 WL = ((const bf16x8*)wf)[(size_t)((0*3+2)*18 + nt*3+kt)*64 + L];
      (void)tbase;
      acc = __builtin_amdgcn_mfma_f32_16x16x32_bf16(aH[kt], WH, acc, 0,0,0);
      acc = __builtin_amdgcn_mfma_f32_16x16x32_bf16(aH[kt], WM, acc, 0,0,0);
      acc = __builtin_amdgcn_mfma_f32_16x16x32_bf16(aM[kt], WH, acc, 0,0,0);
      acc = __builtin_amdgcn_mfma_f32_16x16x32_bf16(aH[kt], WL, acc, 0,0,0);
      acc = __builtin_amdgcn_mfma_f32_16x16x32_bf16(aL[kt], WH, acc, 0,0,0);
      acc = __builtin_amdgcn_mfma_f32_16x16x32_bf16(aM[kt], WM, acc, 0,0,0);
    }
    // C-layout: col = lane&15 (+16*nt), row = quad*4 + reg
    int col = m + 16*nt;
    float bb = msgb[96 + col];
    #pragma unroll
    for (int r=0;r<4;r++)
      tile[w][(4*q + r)*100 + col] = fmaxf(acc[r] + bb, 0.f);
  }
  __syncthreads();

  // ---- reload h1 in A-layout, split-3
  bf16x8 hH[3], hM[3], hL[3];
  #pragma unroll
  for (int kt=0; kt<3; kt++){
    const float4* tp = (const float4*)&tile[w][m*100 + 32*kt + 8*q];
    float4 t0 = tp[0], t1 = tp[1];
    float r[8] = {t0.x,t0.y,t0.z,t0.w,t1.x,t1.y,t1.z,t1.w};
    #pragma unroll
    for (int j=0;j<8;j++){
      short hh,mm,ll; split3(r[j], hh, mm, ll);
      hH[kt][j]=hh; hM[kt][j]=mm; hL[kt][j]=ll;
    }
  }

  // ---- GEMM2 + bias + relu + masked 20-slot aggregation
  #pragma unroll 2
  for (int nt=0; nt<6; nt++){
    f32x4 acc = {0.f,0.f,0.f,0.f};
    #pragma unroll
    for (int kt=0; kt<3; kt++){
      bf16x8 WH = ((const bf16x8*)wf)[(size_t)((1*3+0)*18 + nt*3+kt)*64 + L];
      bf16x8 WM = ((const bf16x8*)wf)[(size_t)((1*3+1)*18 + nt*3+kt)*64 + L];
      bf16x8 WL = ((const bf16x8*)wf)[(size_t)((1*3+2)*18 + nt*3+kt)*64 + L];
      acc = __builtin_amdgcn_mfma_f32_16x16x32_bf16(hH[kt], WH, acc, 0,0,0);
      acc = __builtin_amdgcn_mfma_f32_16x16x32_bf16(hH[kt], WM, acc, 0,0,0);
      acc = __builtin_amdgcn_mfma_f32_16x16x32_bf16(hM[kt], WH, acc, 0,0,0);
      acc = __builtin_amdgcn_mfma_f32_16x16x32_bf16(hH[kt], WL, acc, 0,0,0);
      acc = __builtin_amdgcn_mfma_f32_16x16x32_bf16(hL[kt], WH, acc, 0,0,0);
      acc = __builtin_amdgcn_mfma_f32_16x16x32_bf16(hM[kt], WM, acc, 0,0,0);
    }
    int col = m + 16*nt;
    float bb = msgb[192 + col];
    float p = 0.f;
    #pragma unroll
    for (int r=0;r<4;r++){
      int s = 16*w + 4*q + r;
      float o = fmaxf(acc[r] + bb, 0.f);
      if (s < 20) p += o;
    }
    p += __shfl_xor(p, 16);
    p += __shfl_xor(p, 32);
    if (L < 16) part[w][col] = p;
  }
  __syncthreads();
  if (threadIdx.x < 96){
    float* s2 = ws + O_S2;
    s2[(size_t)n*96 + threadIdx.x] = part[0][threadIdx.x] + part[1][threadIdx.x];
  }
}

// ---------- per-step: LSTM gates + state + next A/B + logits/preds/loss ----------
__global__ __launch_bounds__(192) void k_lstm(float* ws, const int* labels,
                                              const float* msgb,
                                              const float* outW, const float* outb,
                                              float* out, int t)
{
  __shared__ float lh[16*97];
  __shared__ float lgt[160];
  int tid = threadIdx.x; int g = tid/96, j = tid%96;
  int nq = blockIdx.x*2 + g; int n0 = nq*8;
  const float* WX = ws + O_WIHXT;
  const float* WC = ws + O_WCOMBT;
  const float* WH = ws + O_WHHT;
  const float* s2 = ws + O_S2;
  const float* x  = ws + O_X;
  float* h = ws + O_H; float* c = ws + O_C;

  const float hscale = (t == 0) ? 0.f : 1.f;  // scan carry rh starts at 0, not x

  float a0[8],a1[8],a2[8],a3[8];
  {
    float gb0=ws[O_GB+j], gb1=ws[O_GB+96+j], gb2=ws[O_GB+192+j], gb3=ws[O_GB+288+j];
    #pragma unroll
    for (int i=0;i<8;i++){ a0[i]=gb0; a1[i]=gb1; a2[i]=gb2; a3[i]=gb3; }
  }
  #pragma unroll 2
  for (int k=0;k<96;k++){
    float w0=WX[k*384+j], w1=WX[k*384+96+j], w2=WX[k*384+192+j], w3=WX[k*384+288+j];
    #pragma unroll
    for (int i=0;i<8;i++){
      float xv = x[(n0+i)*96+k];
      a0[i]=fmaf(w0,xv,a0[i]); a1[i]=fmaf(w1,xv,a1[i]);
      a2[i]=fmaf(w2,xv,a2[i]); a3[i]=fmaf(w3,xv,a3[i]);
    }
  }
  #pragma unroll 2
  for (int k=0;k<96;k++){
    float c0=WC[k*384+j], c1=WC[k*384+96+j], c2=WC[k*384+192+j], c3=WC[k*384+288+j];
    float h0=WH[k*384+j], h1=WH[k*384+96+j], h2=WH[k*384+192+j], h3=WH[k*384+288+j];
    #pragma unroll
    for (int i=0;i<8;i++){
      float sv = s2[(n0+i)*96+k];
      float rv = h [(n0+i)*96+k] * hscale;
      a0[i]=fmaf(c0,sv,fmaf(h0,rv,a0[i]));
      a1[i]=fmaf(c1,sv,fmaf(h1,rv,a1[i]));
      a2[i]=fmaf(c2,sv,fmaf(h2,rv,a2[i]));
      a3[i]=fmaf(c3,sv,fmaf(h3,rv,a3[i]));
    }
  }
  float nh[8], ncv[8];
  #pragma unroll
  for (int i=0;i<8;i++){
    int n=n0+i;
    float ig=sigm(a0[i]), fg=sigm(a1[i]), gg=tanhf(a2[i]), og=sigm(a3[i]);
    float cv = c[n*96+j];
    float nc = fg*cv + ig*gg;
    float nv = og*tanhf(nc);
    ncv[i]=nc; nh[i]=nv;
    lh[(g*8+i)*97 + j] = nv;
  }
  __syncthreads();
  #pragma unroll
  for (int i=0;i<8;i++){ int n=n0+i; c[n*96+j]=ncv[i]; h[n*96+j]=nh[i]; }

  const float* WA = ws + O_W0AT; const float* WB = ws + O_W0BT;
  float aa[8],ab[8];
  #pragma unroll
  for (int i=0;i<8;i++){ aa[i]=0.f; ab[i]=0.f; }
  #pragma unroll 2
  for (int k=0;k<96;k++){
    float wa=WA[k*96+j], wb=WB[k*96+j];
    #pragma unroll
    for (int i=0;i<8;i++){
      float hv = lh[(g*8+i)*97 + k];
      aa[i]=fmaf(wa,hv,aa[i]); ab[i]=fmaf(wb,hv,ab[i]);
    }
  }
  float* Aa=ws+O_A; float* Bb=ws+O_BV;
  float b0v = msgb[j];
  #pragma unroll
  for (int i=0;i<8;i++){ int n=n0+i; Aa[n*96+j]=aa[i]; Bb[n*96+j]=ab[i]+b0v; }

  if (j < 80){
    int ln = j/10, cls = j%10;
    int n = n0 + ln;
    float q0=outb[cls], q1=0.f, q2=0.f, q3=0.f;
    const float* hr = &lh[(g*8+ln)*97];
    #pragma unroll
    for (int k=0;k<96;k+=4){
      q0=fmaf(outW[cls*96+k  ],hr[k  ],q0); q1=fmaf(outW[cls*96+k+1],hr[k+1],q1);
      q2=fmaf(outW[cls*96+k+2],hr[k+2],q2); q3=fmaf(outW[cls*96+k+3],hr[k+3],q3);
    }
    float lg = (q0+q1)+(q2+q3);
    lgt[(g*8+ln)*10 + cls] = lg;
    out[165889 + (t*NN + n)*10 + cls] = lg;
  }
  __syncthreads();
  if (j < 8){
    int n = n0 + j;
    const float* L = &lgt[(g*8+j)*10];
    float m = L[0]; int bi = 0;
    #pragma unroll
    for (int cc=1;cc<10;cc++){ if (L[cc] > m){ m=L[cc]; bi=cc; } }
    float se = 0.f;
    #pragma unroll
    for (int cc=0;cc<10;cc++) se += expf(L[cc]-m);
    int lab = labels[n];
    float lp = L[lab] - m - logf(se);
    atomicAdd(ws + O_LOSS, -lp);
    out[t*NN + n] = (float)bi;
  }
}

__global__ void k_final(float* ws, float* out){
  if (threadIdx.x == 0 && blockIdx.x == 0)
    out[165888] = ws[O_LOSS] / (float)(TT*NN);
}

extern "C" void kernel_launch(void* const* d_in, const int* in_sizes, int n_in,
                              void* d_out, int out_size, void* d_ws, size_t ws_size,
                              hipStream_t stream)
{
  (void)in_sizes; (void)n_in; (void)out_size; (void)ws_size;
  const int* q      = (const int*)d_in[0];
  const int* row    = (const int*)d_in[1];
  const int* col    = (const int*)d_in[2];
  const int* labels = (const int*)d_in[3];
  const int* dst    = (const int*)d_in[5];
  const float* demb  = (const float*)d_in[6];
  const float* remb  = (const float*)d_in[7];
  const float* cemb  = (const float*)d_in[8];
  const float* inW0  = (const float*)d_in[9];
  const float* inW   = (const float*)d_in[10];
  const float* inb   = (const float*)d_in[11];
  const float* msgW0 = (const float*)d_in[12];
  const float* msgW  = (const float*)d_in[13];
  const float* msgb  = (const float*)d_in[14];
  const float* Wih   = (const float*)d_in[15];
  const float* Whh   = (const float*)d_in[16];
  const float* outW  = (const float*)d_in[17];
  const float* outb  = (const float*)d_in[18];

  float* ws  = (float*)d_ws;
  float* out = (float*)d_out;

  hipLaunchKernelGGL(k_convert, dim3(361), dim3(256), 0, stream, ws, msgW0, Whh, Wih);
  hipLaunchKernelGGL(k_wfrag, dim3(27), dim3(256), 0, stream, ws, msgW);
  hipLaunchKernelGGL(k_wcomb, dim3(144), dim3(256), 0, stream, ws, Wih, msgW, msgb);
  hipLaunchKernelGGL(k_input, dim3(162), dim3(64), 0, stream,
                     ws, q, row, col, demb, remb, cemb, inW0, inW, inb);
  hipLaunchKernelGGL(k_ab0, dim3(648), dim3(192), 0, stream, ws, msgb);
  for (int t=0; t<TT; ++t){
    hipLaunchKernelGGL(k_edge, dim3(NN), dim3(128), 0, stream, ws, dst, msgb);
    hipLaunchKernelGGL(k_lstm, dim3(648), dim3(192), 0, stream,
                       ws, labels, msgb, outW, outb, out, t);
  }
  hipLaunchKernelGGL(k_final, dim3(1), dim3(64), 0, stream, ws, out);
}

// Round 7
// 3460.969 us; speedup vs baseline: 6.8881x; 1.1858x over previous
//
#include <hip/hip_runtime.h>

#define NN 10368
#define EE 207360
#define TT 16

// ---- workspace layout (float offsets) ----
#define O_W0AT    0
#define O_W0BT    9216
#define O_WHHT    18432
#define O_WIHXT   55296
#define O_WCOMBT  92160
#define O_GB      129024
#define O_LOSS    129408
#define O_WIN0T   129424
#define O_WINT    134032
#define O_H       161680
#define O_C       (O_H  + NN*96)
#define O_A       (O_C  + NN*96)
#define O_BV      (O_A  + NN*96)
#define O_S2      (O_BV + NN*96)
#define O_X       (O_S2 + NN*96)
#define O_WFRAG   (O_X  + NN*96)   // ushort region: 2 layers x 3 levels x 18 tiles x 512 shorts
// end = O_WFRAG + 55296 floats = 6,188,944 floats = 24.8 MB

using bf16x8 = __attribute__((ext_vector_type(8))) short;
using f32x4  = __attribute__((ext_vector_type(4))) float;

__device__ __forceinline__ float sigm(float x){ return 1.f/(1.f + expf(-x)); }

__device__ __forceinline__ unsigned rne_bf16(float f){
  unsigned u = __float_as_uint(f);
  u += 0x7fffu + ((u >> 16) & 1u);
  return u >> 16;
}
__device__ __forceinline__ void split3(float x, short& h, short& m, short& l){
  unsigned uh = rne_bf16(x); h = (short)uh;
  float fh = __uint_as_float(uh << 16);
  float r1 = x - fh;
  unsigned um = rne_bf16(r1); m = (short)um;
  float fm = __uint_as_float(um << 16);
  float r2 = r1 - fm;
  l = (short)rne_bf16(r2);
}

// ---------- prep: weight transposes + loss zero ----------
__global__ void k_convert(float* ws, const float* msgW0, const float* Whh, const float* Wih,
                          const float* inW0, const float* inW)
{
  int i = blockIdx.x*256 + threadIdx.x;
  if (i < 9216){ int k=i/96, j=i%96; ws[O_W0AT+i] = msgW0[j*192+k];    return; } i -= 9216;
  if (i < 9216){ int k=i/96, j=i%96; ws[O_W0BT+i] = msgW0[j*192+96+k]; return; } i -= 9216;
  if (i < 36864){ int k=i/384, j=i%384; ws[O_WHHT+i]  = Whh[j*96+k];   return; } i -= 36864;
  if (i < 36864){ int k=i/384, j=i%384; ws[O_WIHXT+i] = Wih[j*192+k];  return; } i -= 36864;
  if (i < 4608){ int k=i/96, j=i%96; ws[O_WIN0T+i] = inW0[j*48+k];     return; } i -= 4608;
  if (i < 27648){ int l=i/9216, r=i%9216; int k=r/96, j=r%96;
                  ws[O_WINT+i] = inW[l*9216 + j*96 + k];               return; } i -= 27648;
  if (i == 0){ ws[O_LOSS] = 0.f; }
}

// ---------- msg W1/W2 -> bf16 split-3 B-fragments for mfma_f32_16x16x32_bf16 ----------
// frag element: B[k=quad*8+j][n=(lane&15)+16*nt] = W[n_out][k], k = 32*kt + quad*8 + j
__global__ void k_wfrag(float* ws, const float* msgW)
{
  int idx = blockIdx.x*256 + threadIdx.x;
  if (idx >= 2*3*18*64) return;
  int lane = idx & 63;
  int tile = (idx >> 6) % 18;
  int lev  = (idx >> 6) / 18 % 3;
  int layer= (idx >> 6) / 54;
  int nt = tile/3, kt = tile%3;
  int nout = (lane & 15) + 16*nt;
  int q = lane >> 4;
  unsigned short* wf = (unsigned short*)(ws + O_WFRAG);
  unsigned short* dstp = wf + (size_t)(((layer*3+lev)*18 + tile)*64 + lane)*8;
  const float* W = msgW + layer*9216;
  for (int j=0;j<8;j++){
    float wv = W[nout*96 + 32*kt + 8*q + j];
    short h,m,l; split3(wv, h, m, l);
    dstp[j] = (unsigned short)(lev==0 ? h : (lev==1 ? m : l));
  }
}

// ---------- Wcomb = W_ih[:,96:] @ msg_W[2]  (fold last msg layer into gates) ----------
__global__ void k_wcomb(float* ws, const float* Wih, const float* msgW, const float* msgb)
{
  int t = blockIdx.x*256 + threadIdx.x;
  if (t >= 36864) return;
  int j = t % 384, qq = t / 384;
  float a0=0.f,a1=0.f,a2=0.f,a3=0.f;
  for (int r=0;r<96;r+=4){
    a0 = fmaf(Wih[j*192+96+r  ], msgW[2*9216+(r  )*96+qq], a0);
    a1 = fmaf(Wih[j*192+96+r+1], msgW[2*9216+(r+1)*96+qq], a1);
    a2 = fmaf(Wih[j*192+96+r+2], msgW[2*9216+(r+2)*96+qq], a2);
    a3 = fmaf(Wih[j*192+96+r+3], msgW[2*9216+(r+3)*96+qq], a3);
  }
  ws[O_WCOMBT + qq*384 + j] = (a0+a1)+(a2+a3);
  if (qq == 0){
    float g=0.f;
    for (int r=0;r<96;r++) g = fmaf(Wih[j*192+96+r], msgb[288+r], g);
    ws[O_GB + j] = 20.f * g;
  }
}

// ---------- input MLP (j-parallel) + fused step-0 A/B ----------
// block = 192 thr = 2 groups x 96; group g handles 8 nodes; thread j = feature j.
__global__ __launch_bounds__(192) void k_input(float* ws,
    const int* q, const int* row, const int* col,
    const float* demb, const float* remb, const float* cemb,
    const float* inb, const float* msgb)
{
  __shared__ float ein[2][8*49];
  __shared__ float hb[2][8*97];
  int tid = threadIdx.x; int g = tid/96, j = tid%96;
  int nq = blockIdx.x*2 + g; int n0 = nq*8;

  for (int idx=j; idx<384; idx+=96){
    int i = idx/48, f = idx%48; int n = n0+i;
    float v;
    if (f < 16)      v = demb[q[n]*16 + f];
    else if (f < 32) v = remb[row[n]*16 + (f-16)];
    else             v = cemb[col[n]*16 + (f-32)];
    ein[g][i*49+f] = v;
  }
  __syncthreads();

  float acc[8];
  {
    const float* W0T = ws + O_WIN0T;
    float b0 = inb[j];
    #pragma unroll
    for (int i=0;i<8;i++) acc[i]=b0;
    #pragma unroll 2
    for (int k=0;k<48;k++){
      float w = W0T[k*96+j];
      #pragma unroll
      for (int i=0;i<8;i++) acc[i] = fmaf(w, ein[g][i*49+k], acc[i]);
    }
    #pragma unroll
    for (int i=0;i<8;i++) hb[g][i*97+j] = fmaxf(acc[i], 0.f);
  }
  __syncthreads();

  for (int l=0;l<3;l++){
    const float* WT = ws + O_WINT + l*9216;
    float bl = inb[(l+1)*96 + j];
    #pragma unroll
    for (int i=0;i<8;i++) acc[i]=bl;
    #pragma unroll 2
    for (int k=0;k<96;k++){
      float w = WT[k*96+j];
      #pragma unroll
      for (int i=0;i<8;i++) acc[i] = fmaf(w, hb[g][i*97+k], acc[i]);
    }
    __syncthreads();
    if (l < 2){
      #pragma unroll
      for (int i=0;i<8;i++) hb[g][i*97+j] = fmaxf(acc[i], 0.f);
    } else {
      #pragma unroll
      for (int i=0;i<8;i++) hb[g][i*97+j] = acc[i];
    }
    __syncthreads();
  }

  // write h = x = h0, c = 0
  float* h = ws + O_H; float* c = ws + O_C; float* x = ws + O_X;
  #pragma unroll
  for (int i=0;i<8;i++){
    int n = n0+i;
    float vv = hb[g][i*97+j];
    h[n*96+j]=vv; x[n*96+j]=vv; c[n*96+j]=0.f;
  }
  // fused step-0 A/B
  const float* WA = ws + O_W0AT; const float* WB = ws + O_W0BT;
  float aa[8], ab[8];
  #pragma unroll
  for (int i=0;i<8;i++){ aa[i]=0.f; ab[i]=0.f; }
  #pragma unroll 2
  for (int k=0;k<96;k++){
    float wa=WA[k*96+j], wb=WB[k*96+j];
    #pragma unroll
    for (int i=0;i<8;i++){
      float hv = hb[g][i*97+k];
      aa[i]=fmaf(wa,hv,aa[i]); ab[i]=fmaf(wb,hv,ab[i]);
    }
  }
  float* A=ws+O_A; float* Bv=ws+O_BV;
  float b0v = msgb[j];
  #pragma unroll
  for (int i=0;i<8;i++){ int n=n0+i; A[n*96+j]=aa[i]; Bv[n*96+j]=ab[i]+b0v; }
}

// ---------- per-step edge MLP via bf16 split-3 MFMA, 4 nodes/block ----------
// block = 4 nodes = 80 edges = 5 waves x 16 slots (zero padding).
// s2[n] = sum_{s<20} relu(W2 relu(W1 relu(A[dst[n*20+s]] + B[n]) + b1) + b2)
__global__ __launch_bounds__(320) void k_edge(float* ws, const int* dst, const float* msgb)
{
  __shared__ float tile[5][16*100];   // per-wave h1 relayout tile
  __shared__ float part[5][2][96];    // per-wave lo/hi node partials
  int w = threadIdx.x >> 6;
  int L = threadIdx.x & 63;
  int m = L & 15, q = L >> 4;
  int gs = w*16 + m;                  // global slot in [0,80)
  int e  = blockIdx.x*80 + gs;        // EE = 2592*80 exactly
  int v  = dst[e];
  int n  = blockIdx.x*4 + gs/20;

  const float* Aact = ws + O_A;
  const float* Bact = ws + O_BV;
  const unsigned short* wf = (const unsigned short*)(ws + O_WFRAG);

  // ---- A-fragments of vin = relu(A[v]+B[n]) : layout A[m=lane&15][k=quad*8+j]
  bf16x8 aH[3], aM[3], aL[3];
  #pragma unroll
  for (int kt=0; kt<3; kt++){
    int k0 = 32*kt + 8*q;
    float4 a0 = *(const float4*)(Aact + (size_t)v*96 + k0);
    float4 a1 = *(const float4*)(Aact + (size_t)v*96 + k0 + 4);
    float4 b0 = *(const float4*)(Bact + (size_t)n*96 + k0);
    float4 b1 = *(const float4*)(Bact + (size_t)n*96 + k0 + 4);
    float r[8];
    r[0]=fmaxf(a0.x+b0.x,0.f); r[1]=fmaxf(a0.y+b0.y,0.f);
    r[2]=fmaxf(a0.z+b0.z,0.f); r[3]=fmaxf(a0.w+b0.w,0.f);
    r[4]=fmaxf(a1.x+b1.x,0.f); r[5]=fmaxf(a1.y+b1.y,0.f);
    r[6]=fmaxf(a1.z+b1.z,0.f); r[7]=fmaxf(a1.w+b1.w,0.f);
    #pragma unroll
    for (int j=0;j<8;j++){
      short hh,mm,ll; split3(r[j], hh, mm, ll);
      aH[kt][j]=hh; aM[kt][j]=mm; aL[kt][j]=ll;
    }
  }

  // ---- GEMM1: h1 = relu(vin @ W1^T + b1) -> wave-private LDS tile
  #pragma unroll 2
  for (int nt=0; nt<6; nt++){
    f32x4 acc = {0.f,0.f,0.f,0.f};
    #pragma unroll
    for (int kt=0; kt<3; kt++){
      bf16x8 WH = ((const bf16x8*)wf)[(size_t)((0*3+0)*18 + nt*3+kt)*64 + L];
      bf16x8 WM = ((const bf16x8*)wf)[(size_t)((0*3+1)*18 + nt*3+kt)*64 + L];
      bf16x8 WL = ((const bf16x8*)wf)[(size_t)((0*3+2)*18 + nt*3+kt)*64 + L];
      acc = __builtin_amdgcn_mfma_f32_16x16x32_bf16(aH[kt], WH, acc, 0,0,0);
      acc = __builtin_amdgcn_mfma_f32_16x16x32_bf16(aH[kt], WM, acc, 0,0,0);
      acc = __builtin_amdgcn_mfma_f32_16x16x32_bf16(aM[kt], WH, acc, 0,0,0);
      acc = __builtin_amdgcn_mfma_f32_16x16x32_bf16(aH[kt], WL, acc, 0,0,0);
      acc = __builtin_amdgcn_mfma_f32_16x16x32_bf16(aL[kt], WH, acc, 0,0,0);
      acc = __builtin_amdgcn_mfma_f32_16x16x32_bf16(aM[kt], WM, acc, 0,0,0);
    }
    int col = m + 16*nt;                 // C-layout: col=lane&15, row=quad*4+reg
    float bb = msgb[96 + col];
    #pragma unroll
    for (int r=0;r<4;r++)
      tile[w][(4*q + r)*100 + col] = fmaxf(acc[r] + bb, 0.f);
  }
  __syncthreads();

  // ---- reload h1 in A-layout, split-3
  bf16x8 hH[3], hM[3], hL[3];
  #pragma unroll
  for (int kt=0; kt<3; kt++){
    const float4* tp = (const float4*)&tile[w][m*100 + 32*kt + 8*q];
    float4 t0 = tp[0], t1 = tp[1];
    float r[8] = {t0.x,t0.y,t0.z,t0.w,t1.x,t1.y,t1.z,t1.w};
    #pragma unroll
    for (int j=0;j<8;j++){
      short hh,mm,ll; split3(r[j], hh, mm, ll);
      hH[kt][j]=hh; hM[kt][j]=mm; hL[kt][j]=ll;
    }
  }

  // ---- GEMM2 + bias + relu + segmented (lo/hi node) aggregation
  int lo_node = (w*16)/20;
  #pragma unroll 2
  for (int nt=0; nt<6; nt++){
    f32x4 acc = {0.f,0.f,0.f,0.f};
    #pragma unroll
    for (int kt=0; kt<3; kt++){
      bf16x8 WH = ((const bf16x8*)wf)[(size_t)((1*3+0)*18 + nt*3+kt)*64 + L];
      bf16x8 WM = ((const bf16x8*)wf)[(size_t)((1*3+1)*18 + nt*3+kt)*64 + L];
      bf16x8 WL = ((const bf16x8*)wf)[(size_t)((1*3+2)*18 + nt*3+kt)*64 + L];
      acc = __builtin_amdgcn_mfma_f32_16x16x32_bf16(hH[kt], WH, acc, 0,0,0);
      acc = __builtin_amdgcn_mfma_f32_16x16x32_bf16(hH[kt], WM, acc, 0,0,0);
      acc = __builtin_amdgcn_mfma_f32_16x16x32_bf16(hM[kt], WH, acc, 0,0,0);
      acc = __builtin_amdgcn_mfma_f32_16x16x32_bf16(hH[kt], WL, acc, 0,0,0);
      acc = __builtin_amdgcn_mfma_f32_16x16x32_bf16(hL[kt], WH, acc, 0,0,0);
      acc = __builtin_amdgcn_mfma_f32_16x16x32_bf16(hM[kt], WM, acc, 0,0,0);
    }
    int col = m + 16*nt;
    float bb = msgb[192 + col];
    float plo = 0.f, phi = 0.f;
    #pragma unroll
    for (int r=0;r<4;r++){
      int s = w*16 + 4*q + r;          // row = slot within this wave's 16
      float o = fmaxf(acc[r] + bb, 0.f);
      if (s/20 == lo_node) plo += o; else phi += o;
    }
    plo += __shfl_xor(plo, 16); plo += __shfl_xor(plo, 32);
    phi += __shfl_xor(phi, 16); phi += __shfl_xor(phi, 32);
    if (L < 16){ part[w][0][col] = plo; part[w][1][col] = phi; }
  }
  __syncthreads();
  // merge: node d gets lo of waves with lo(w)==d, hi of waves with hi(w)==d (!=lo)
  float* s2 = ws + O_S2;
  for (int idx = threadIdx.x; idx < 384; idx += 320){
    int nd = idx/96, col = idx%96;
    float s = 0.f;
    #pragma unroll
    for (int w2=0; w2<5; w2++){
      int lo = (w2*16)/20, hi = (w2*16+15)/20;
      if (lo == nd)       s += part[w2][0][col];
      else if (hi == nd)  s += part[w2][1][col];
    }
    s2[(size_t)(blockIdx.x*4+nd)*96 + col] = s;
  }
}

// ---------- per-step: LSTM gates + state + next A/B + logits/preds/loss ----------
__global__ __launch_bounds__(192) void k_lstm(float* ws, const int* labels,
                                              const float* msgb,
                                              const float* outW, const float* outb,
                                              float* out, int t)
{
  __shared__ float lh[16*97];
  __shared__ float lgt[160];
  int tid = threadIdx.x; int g = tid/96, j = tid%96;
  int nq = blockIdx.x*2 + g; int n0 = nq*8;
  const float* WX = ws + O_WIHXT;
  const float* WC = ws + O_WCOMBT;
  const float* WH = ws + O_WHHT;
  const float* s2 = ws + O_S2;
  const float* x  = ws + O_X;
  float* h = ws + O_H; float* c = ws + O_C;

  const float hscale = (t == 0) ? 0.f : 1.f;  // scan carry rh starts at 0, not x

  float a0[8],a1[8],a2[8],a3[8];
  {
    float gb0=ws[O_GB+j], gb1=ws[O_GB+96+j], gb2=ws[O_GB+192+j], gb3=ws[O_GB+288+j];
    #pragma unroll
    for (int i=0;i<8;i++){ a0[i]=gb0; a1[i]=gb1; a2[i]=gb2; a3[i]=gb3; }
  }
  #pragma unroll 2
  for (int k=0;k<96;k++){
    float w0=WX[k*384+j], w1=WX[k*384+96+j], w2=WX[k*384+192+j], w3=WX[k*384+288+j];
    #pragma unroll
    for (int i=0;i<8;i++){
      float xv = x[(n0+i)*96+k];
      a0[i]=fmaf(w0,xv,a0[i]); a1[i]=fmaf(w1,xv,a1[i]);
      a2[i]=fmaf(w2,xv,a2[i]); a3[i]=fmaf(w3,xv,a3[i]);
    }
  }
  #pragma unroll 2
  for (int k=0;k<96;k++){
    float c0=WC[k*384+j], c1=WC[k*384+96+j], c2=WC[k*384+192+j], c3=WC[k*384+288+j];
    float h0=WH[k*384+j], h1=WH[k*384+96+j], h2=WH[k*384+192+j], h3=WH[k*384+288+j];
    #pragma unroll
    for (int i=0;i<8;i++){
      float sv = s2[(n0+i)*96+k];
      float rv = h [(n0+i)*96+k] * hscale;
      a0[i]=fmaf(c0,sv,fmaf(h0,rv,a0[i]));
      a1[i]=fmaf(c1,sv,fmaf(h1,rv,a1[i]));
      a2[i]=fmaf(c2,sv,fmaf(h2,rv,a2[i]));
      a3[i]=fmaf(c3,sv,fmaf(h3,rv,a3[i]));
    }
  }
  float nh[8], ncv[8];
  #pragma unroll
  for (int i=0;i<8;i++){
    int n=n0+i;
    float ig=sigm(a0[i]), fg=sigm(a1[i]), gg=tanhf(a2[i]), og=sigm(a3[i]);
    float cv = c[n*96+j];
    float nc = fg*cv + ig*gg;
    float nv = og*tanhf(nc);
    ncv[i]=nc; nh[i]=nv;
    lh[(g*8+i)*97 + j] = nv;
  }
  __syncthreads();
  #pragma unroll
  for (int i=0;i<8;i++){ int n=n0+i; c[n*96+j]=ncv[i]; h[n*96+j]=nh[i]; }

  const float* WA = ws + O_W0AT; const float* WB = ws + O_W0BT;
  float aa[8],ab[8];
  #pragma unroll
  for (int i=0;i<8;i++){ aa[i]=0.f; ab[i]=0.f; }
  #pragma unroll 2
  for (int k=0;k<96;k++){
    float wa=WA[k*96+j], wb=WB[k*96+j];
    #pragma unroll
    for (int i=0;i<8;i++){
      float hv = lh[(g*8+i)*97 + k];
      aa[i]=fmaf(wa,hv,aa[i]); ab[i]=fmaf(wb,hv,ab[i]);
    }
  }
  float* Aa=ws+O_A; float* Bb=ws+O_BV;
  float b0v = msgb[j];
  #pragma unroll
  for (int i=0;i<8;i++){ int n=n0+i; Aa[n*96+j]=aa[i]; Bb[n*96+j]=ab[i]+b0v; }

  if (j < 80){
    int ln = j/10, cls = j%10;
    int n = n0 + ln;
    float q0=outb[cls], q1=0.f, q2=0.f, q3=0.f;
    const float* hr = &lh[(g*8+ln)*97];
    #pragma unroll
    for (int k=0;k<96;k+=4){
      q0=fmaf(outW[cls*96+k  ],hr[k  ],q0); q1=fmaf(outW[cls*96+k+1],hr[k+1],q1);
      q2=fmaf(outW[cls*96+k+2],hr[k+2],q2); q3=fmaf(outW[cls*96+k+3],hr[k+3],q3);
    }
    float lg = (q0+q1)+(q2+q3);
    lgt[(g*8+ln)*10 + cls] = lg;
    out[165889 + (t*NN + n)*10 + cls] = lg;
  }
  __syncthreads();
  if (j < 8){
    int n = n0 + j;
    const float* L = &lgt[(g*8+j)*10];
    float m = L[0]; int bi = 0;
    #pragma unroll
    for (int cc=1;cc<10;cc++){ if (L[cc] > m){ m=L[cc]; bi=cc; } }
    float se = 0.f;
    #pragma unroll
    for (int cc=0;cc<10;cc++) se += expf(L[cc]-m);
    int lab = labels[n];
    float lp = L[lab] - m - logf(se);
    atomicAdd(ws + O_LOSS, -lp);
    out[t*NN + n] = (float)bi;
  }
}

__global__ void k_final(float* ws, float* out){
  if (threadIdx.x == 0 && blockIdx.x == 0)
    out[165888] = ws[O_LOSS] / (float)(TT*NN);
}

extern "C" void kernel_launch(void* const* d_in, const int* in_sizes, int n_in,
                              void* d_out, int out_size, void* d_ws, size_t ws_size,
                              hipStream_t stream)
{
  (void)in_sizes; (void)n_in; (void)out_size; (void)ws_size;
  const int* q      = (const int*)d_in[0];
  const int* row    = (const int*)d_in[1];
  const int* col    = (const int*)d_in[2];
  const int* labels = (const int*)d_in[3];
  const int* dst    = (const int*)d_in[5];
  const float* demb  = (const float*)d_in[6];
  const float* remb  = (const float*)d_in[7];
  const float* cemb  = (const float*)d_in[8];
  const float* inW0  = (const float*)d_in[9];
  const float* inW   = (const float*)d_in[10];
  const float* inb   = (const float*)d_in[11];
  const float* msgW0 = (const float*)d_in[12];
  const float* msgW  = (const float*)d_in[13];
  const float* msgb  = (const float*)d_in[14];
  const float* Wih   = (const float*)d_in[15];
  const float* Whh   = (const float*)d_in[16];
  const float* outW  = (const float*)d_in[17];
  const float* outb  = (const float*)d_in[18];

  float* ws  = (float*)d_ws;
  float* out = (float*)d_out;

  hipLaunchKernelGGL(k_convert, dim3(487), dim3(256), 0, stream,
                     ws, msgW0, Whh, Wih, inW0, inW);
  hipLaunchKernelGGL(k_wfrag, dim3(27), dim3(256), 0, stream, ws, msgW);
  hipLaunchKernelGGL(k_wcomb, dim3(144), dim3(256), 0, stream, ws, Wih, msgW, msgb);
  hipLaunchKernelGGL(k_input, dim3(648), dim3(192), 0, stream,
                     ws, q, row, col, demb, remb, cemb, inb, msgb);
  for (int t=0; t<TT; ++t){
    hipLaunchKernelGGL(k_edge, dim3(EE/80), dim3(320), 0, stream, ws, dst, msgb);
    hipLaunchKernelGGL(k_lstm, dim3(648), dim3(192), 0, stream,
                       ws, labels, msgb, outW, outb, out, t);
  }
  hipLaunchKernelGGL(k_final, dim3(1), dim3(64), 0, stream, ws, out);
}

// Round 10
// 3128.873 us; speedup vs baseline: 7.6192x; 1.1061x over previous
//
#include <hip/hip_runtime.h>

#define NN 10368
#define EE 207360
#define TT 16

// ---- workspace layout (float offsets) ---- (r7-verified layout, 24.65 MB)
#define O_W0AT    0
#define O_W0BT    9216
#define O_WHHT    18432
#define O_WIHXT   55296
#define O_WCOMBT  92160
#define O_GB      129024
#define O_LOSS    129408
#define O_WIN0T   129424
#define O_WINT    134032
#define O_H       161680
#define O_C       (O_H  + NN*96)
#define O_A       (O_C  + NN*96)
#define O_BV      (O_A  + NN*96)
#define O_S2      (O_BV + NN*96)
#define O_X       (O_S2 + NN*96)
#define O_WFRAG   (O_X  + NN*96)   // ushort region: 2 layers x 3 levels x 18 tiles x 512 shorts

using bf16x8 = __attribute__((ext_vector_type(8))) short;
using f32x4  = __attribute__((ext_vector_type(4))) float;

__device__ __forceinline__ float sigm(float x){ return 1.f/(1.f + expf(-x)); }

__device__ __forceinline__ unsigned rne_bf16(float f){
  unsigned u = __float_as_uint(f);
  u += 0x7fffu + ((u >> 16) & 1u);
  return u >> 16;
}
__device__ __forceinline__ void split3(float x, short& h, short& m, short& l){
  unsigned uh = rne_bf16(x); h = (short)uh;
  float fh = __uint_as_float(uh << 16);
  float r1 = x - fh;
  unsigned um = rne_bf16(r1); m = (short)um;
  float fm = __uint_as_float(um << 16);
  float r2 = r1 - fm;
  l = (short)rne_bf16(r2);
}

// ---------- prep: weight transposes + loss zero ----------
__global__ void k_convert(float* ws, const float* msgW0, const float* Whh, const float* Wih,
                          const float* inW0, const float* inW)
{
  int i = blockIdx.x*256 + threadIdx.x;
  if (i < 9216){ int k=i/96, j=i%96; ws[O_W0AT+i] = msgW0[j*192+k];    return; } i -= 9216;
  if (i < 9216){ int k=i/96, j=i%96; ws[O_W0BT+i] = msgW0[j*192+96+k]; return; } i -= 9216;
  if (i < 36864){ int k=i/384, j=i%384; ws[O_WHHT+i]  = Whh[j*96+k];   return; } i -= 36864;
  if (i < 36864){ int k=i/384, j=i%384; ws[O_WIHXT+i] = Wih[j*192+k];  return; } i -= 36864;
  if (i < 4608){ int k=i/96, j=i%96; ws[O_WIN0T+i] = inW0[j*48+k];     return; } i -= 4608;
  if (i < 27648){ int l=i/9216, r=i%9216; int k=r/96, j=r%96;
                  ws[O_WINT+i] = inW[l*9216 + j*96 + k];               return; } i -= 27648;
  if (i == 0){ ws[O_LOSS] = 0.f; }
}

// ---------- msg W1/W2 -> bf16 split-3 B-fragments (edge kernel) ----------
__global__ void k_wfrag(float* ws, const float* msgW)
{
  int idx = blockIdx.x*256 + threadIdx.x;
  if (idx >= 2*3*18*64) return;
  int lane = idx & 63;
  int tile = (idx >> 6) % 18;
  int lev  = (idx >> 6) / 18 % 3;
  int layer= (idx >> 6) / 54;
  int nt = tile/3, kt = tile%3;
  int nout = (lane & 15) + 16*nt;
  int q = lane >> 4;
  unsigned short* wf = (unsigned short*)(ws + O_WFRAG);
  unsigned short* dstp = wf + (size_t)(((layer*3+lev)*18 + tile)*64 + lane)*8;
  const float* W = msgW + layer*9216;
  for (int j=0;j<8;j++){
    float wv = W[nout*96 + 32*kt + 8*q + j];
    short h,m,l; split3(wv, h, m, l);
    dstp[j] = (unsigned short)(lev==0 ? h : (lev==1 ? m : l));
  }
}

// ---------- Wcomb = W_ih[:,96:] @ msg_W[2]  (fold last msg layer into gates) ----------
__global__ void k_wcomb(float* ws, const float* Wih, const float* msgW, const float* msgb)
{
  int t = blockIdx.x*256 + threadIdx.x;
  if (t >= 36864) return;
  int j = t % 384, qq = t / 384;
  float a0=0.f,a1=0.f,a2=0.f,a3=0.f;
  for (int r=0;r<96;r+=4){
    a0 = fmaf(Wih[j*192+96+r  ], msgW[2*9216+(r  )*96+qq], a0);
    a1 = fmaf(Wih[j*192+96+r+1], msgW[2*9216+(r+1)*96+qq], a1);
    a2 = fmaf(Wih[j*192+96+r+2], msgW[2*9216+(r+2)*96+qq], a2);
    a3 = fmaf(Wih[j*192+96+r+3], msgW[2*9216+(r+3)*96+qq], a3);
  }
  ws[O_WCOMBT + qq*384 + j] = (a0+a1)+(a2+a3);
  if (qq == 0){
    float g=0.f;
    for (int r=0;r<96;r++) g = fmaf(Wih[j*192+96+r], msgb[288+r], g);
    ws[O_GB + j] = 20.f * g;
  }
}

// ---------- input MLP (j-parallel) + fused step-0 A/B ----------
__global__ __launch_bounds__(192) void k_input(float* ws,
    const int* q, const int* row, const int* col,
    const float* demb, const float* remb, const float* cemb,
    const float* inb, const float* msgb)
{
  __shared__ float ein[2][8*49];
  __shared__ float hb[2][8*97];
  int tid = threadIdx.x; int g = tid/96, j = tid%96;
  int nq = blockIdx.x*2 + g; int n0 = nq*8;

  for (int idx=j; idx<384; idx+=96){
    int i = idx/48, f = idx%48; int n = n0+i;
    float v;
    if (f < 16)      v = demb[q[n]*16 + f];
    else if (f < 32) v = remb[row[n]*16 + (f-16)];
    else             v = cemb[col[n]*16 + (f-32)];
    ein[g][i*49+f] = v;
  }
  __syncthreads();

  float acc[8];
  {
    const float* W0T = ws + O_WIN0T;
    float b0 = inb[j];
    #pragma unroll
    for (int i=0;i<8;i++) acc[i]=b0;
    #pragma unroll 2
    for (int k=0;k<48;k++){
      float w = W0T[k*96+j];
      #pragma unroll
      for (int i=0;i<8;i++) acc[i] = fmaf(w, ein[g][i*49+k], acc[i]);
    }
    #pragma unroll
    for (int i=0;i<8;i++) hb[g][i*97+j] = fmaxf(acc[i], 0.f);
  }
  __syncthreads();

  for (int l=0;l<3;l++){
    const float* WT = ws + O_WINT + l*9216;
    float bl = inb[(l+1)*96 + j];
    #pragma unroll
    for (int i=0;i<8;i++) acc[i]=bl;
    #pragma unroll 2
    for (int k=0;k<96;k++){
      float w = WT[k*96+j];
      #pragma unroll
      for (int i=0;i<8;i++) acc[i] = fmaf(w, hb[g][i*97+k], acc[i]);
    }
    __syncthreads();
    if (l < 2){
      #pragma unroll
      for (int i=0;i<8;i++) hb[g][i*97+j] = fmaxf(acc[i], 0.f);
    } else {
      #pragma unroll
      for (int i=0;i<8;i++) hb[g][i*97+j] = acc[i];
    }
    __syncthreads();
  }

  float* h = ws + O_H; float* c = ws + O_C; float* x = ws + O_X;
  #pragma unroll
  for (int i=0;i<8;i++){
    int n = n0+i;
    float vv = hb[g][i*97+j];
    h[n*96+j]=vv; x[n*96+j]=vv; c[n*96+j]=0.f;
  }
  const float* WA = ws + O_W0AT; const float* WB = ws + O_W0BT;
  float aa[8], ab[8];
  #pragma unroll
  for (int i=0;i<8;i++){ aa[i]=0.f; ab[i]=0.f; }
  #pragma unroll 2
  for (int k=0;k<96;k++){
    float wa=WA[k*96+j], wb=WB[k*96+j];
    #pragma unroll
    for (int i=0;i<8;i++){
      float hv = hb[g][i*97+k];
      aa[i]=fmaf(wa,hv,aa[i]); ab[i]=fmaf(wb,hv,ab[i]);
    }
  }
  float* A=ws+O_A; float* Bv=ws+O_BV;
  float b0v = msgb[j];
  #pragma unroll
  for (int i=0;i<8;i++){ int n=n0+i; A[n*96+j]=aa[i]; Bv[n*96+j]=ab[i]+b0v; }
}

// ---------- per-step edge MLP via bf16 split-3 MFMA, 4 nodes/block (r7-verified) ----------
__global__ __launch_bounds__(320) void k_edge(float* ws, const int* dst, const float* msgb)
{
  __shared__ float tile[5][16*100];
  __shared__ float part[5][2][96];
  int w = threadIdx.x >> 6;
  int L = threadIdx.x & 63;
  int m = L & 15, q = L >> 4;
  int gs = w*16 + m;
  int e  = blockIdx.x*80 + gs;
  int v  = dst[e];
  int n  = blockIdx.x*4 + gs/20;

  const float* Aact = ws + O_A;
  const float* Bact = ws + O_BV;
  const unsigned short* wf = (const unsigned short*)(ws + O_WFRAG);

  bf16x8 aH[3], aM[3], aL[3];
  #pragma unroll
  for (int kt=0; kt<3; kt++){
    int k0 = 32*kt + 8*q;
    float4 a0 = *(const float4*)(Aact + (size_t)v*96 + k0);
    float4 a1 = *(const float4*)(Aact + (size_t)v*96 + k0 + 4);
    float4 b0 = *(const float4*)(Bact + (size_t)n*96 + k0);
    float4 b1 = *(const float4*)(Bact + (size_t)n*96 + k0 + 4);
    float r[8];
    r[0]=fmaxf(a0.x+b0.x,0.f); r[1]=fmaxf(a0.y+b0.y,0.f);
    r[2]=fmaxf(a0.z+b0.z,0.f); r[3]=fmaxf(a0.w+b0.w,0.f);
    r[4]=fmaxf(a1.x+b1.x,0.f); r[5]=fmaxf(a1.y+b1.y,0.f);
    r[6]=fmaxf(a1.z+b1.z,0.f); r[7]=fmaxf(a1.w+b1.w,0.f);
    #pragma unroll
    for (int j=0;j<8;j++){
      short hh,mm,ll; split3(r[j], hh, mm, ll);
      aH[kt][j]=hh; aM[kt][j]=mm; aL[kt][j]=ll;
    }
  }

  #pragma unroll 2
  for (int nt=0; nt<6; nt++){
    f32x4 acc = {0.f,0.f,0.f,0.f};
    #pragma unroll
    for (int kt=0; kt<3; kt++){
      bf16x8 WH = ((const bf16x8*)wf)[(size_t)((0*3+0)*18 + nt*3+kt)*64 + L];
      bf16x8 WM = ((const bf16x8*)wf)[(size_t)((0*3+1)*18 + nt*3+kt)*64 + L];
      bf16x8 WL = ((const bf16x8*)wf)[(size_t)((0*3+2)*18 + nt*3+kt)*64 + L];
      acc = __builtin_amdgcn_mfma_f32_16x16x32_bf16(aH[kt], WH, acc, 0,0,0);
      acc = __builtin_amdgcn_mfma_f32_16x16x32_bf16(aH[kt], WM, acc, 0,0,0);
      acc = __builtin_amdgcn_mfma_f32_16x16x32_bf16(aM[kt], WH, acc, 0,0,0);
      acc = __builtin_amdgcn_mfma_f32_16x16x32_bf16(aH[kt], WL, acc, 0,0,0);
      acc = __builtin_amdgcn_mfma_f32_16x16x32_bf16(aL[kt], WH, acc, 0,0,0);
      acc = __builtin_amdgcn_mfma_f32_16x16x32_bf16(aM[kt], WM, acc, 0,0,0);
    }
    int col = m + 16*nt;
    float bb = msgb[96 + col];
    #pragma unroll
    for (int r=0;r<4;r++)
      tile[w][(4*q + r)*100 + col] = fmaxf(acc[r] + bb, 0.f);
  }
  __syncthreads();

  bf16x8 hH[3], hM[3], hL[3];
  #pragma unroll
  for (int kt=0; kt<3; kt++){
    const float4* tp = (const float4*)&tile[w][m*100 + 32*kt + 8*q];
    float4 t0 = tp[0], t1 = tp[1];
    float r[8] = {t0.x,t0.y,t0.z,t0.w,t1.x,t1.y,t1.z,t1.w};
    #pragma unroll
    for (int j=0;j<8;j++){
      short hh,mm,ll; split3(r[j], hh, mm, ll);
      hH[kt][j]=hh; hM[kt][j]=mm; hL[kt][j]=ll;
    }
  }

  int lo_node = (w*16)/20;
  #pragma unroll 2
  for (int nt=0; nt<6; nt++){
    f32x4 acc = {0.f,0.f,0.f,0.f};
    #pragma unroll
    for (int kt=0; kt<3; kt++){
      bf16x8 WH = ((const bf16x8*)wf)[(size_t)((1*3+0)*18 + nt*3+kt)*64 + L];
      bf16x8 WM = ((const bf16x8*)wf)[(size_t)((1*3+1)*18 + nt*3+kt)*64 + L];
      bf16x8 WL = ((const bf16x8*)wf)[(size_t)((1*3+2)*18 + nt*3+kt)*64 + L];
      acc = __builtin_amdgcn_mfma_f32_16x16x32_bf16(hH[kt], WH, acc, 0,0,0);
      acc = __builtin_amdgcn_mfma_f32_16x16x32_bf16(hH[kt], WM, acc, 0,0,0);
      acc = __builtin_amdgcn_mfma_f32_16x16x32_bf16(hM[kt], WH, acc, 0,0,0);
      acc = __builtin_amdgcn_mfma_f32_16x16x32_bf16(hH[kt], WL, acc, 0,0,0);
      acc = __builtin_amdgcn_mfma_f32_16x16x32_bf16(hL[kt], WH, acc, 0,0,0);
      acc = __builtin_amdgcn_mfma_f32_16x16x32_bf16(hM[kt], WM, acc, 0,0,0);
    }
    int col = m + 16*nt;
    float bb = msgb[192 + col];
    float plo = 0.f, phi = 0.f;
    #pragma unroll
    for (int r=0;r<4;r++){
      int s = w*16 + 4*q + r;
      float o = fmaxf(acc[r] + bb, 0.f);
      if (s/20 == lo_node) plo += o; else phi += o;
    }
    plo += __shfl_xor(plo, 16); plo += __shfl_xor(plo, 32);
    phi += __shfl_xor(phi, 16); phi += __shfl_xor(phi, 32);
    if (L < 16){ part[w][0][col] = plo; part[w][1][col] = phi; }
  }
  __syncthreads();
  float* s2 = ws + O_S2;
  for (int idx = threadIdx.x; idx < 384; idx += 320){
    int nd = idx/96, col = idx%96;
    float s = 0.f;
    #pragma unroll
    for (int w2=0; w2<5; w2++){
      int lo = (w2*16)/20, hi = (w2*16+15)/20;
      if (lo == nd)       s += part[w2][0][col];
      else if (hi == nd)  s += part[w2][1][col];
    }
    s2[(size_t)(blockIdx.x*4+nd)*96 + col] = s;
  }
}

// ---------- per-step LSTM (r7 arithmetic, 8 nodes/block + LDS act staging) ----------
// grid 1296; block 192 = 2 groups x 96; group g handles 4 nodes; thread j = gate feature j.
__global__ __launch_bounds__(192) void k_lstm(float* ws, const int* labels,
                                              const float* msgb,
                                              const float* outW, const float* outb,
                                              float* out, int t)
{
  __shared__ float sx[8*96], ss[8*96], sh[8*96];
  __shared__ float lh[8*97];
  __shared__ float lgt[80];
  int tid = threadIdx.x; int g = tid/96, j = tid%96;
  int nb = blockIdx.x*8;          // block's first node
  int n0 = nb + g*4;              // group's first node
  const float* WX = ws + O_WIHXT;
  const float* WC = ws + O_WCOMBT;
  const float* WH = ws + O_WHHT;
  float* h = ws + O_H; float* c = ws + O_C;

  const float hscale = (t == 0) ? 0.f : 1.f;  // scan carry rh starts at 0, not x

  // stage acts for the block's 8 nodes (coalesced)
  for (int idx = tid; idx < 768; idx += 192){
    sx[idx] = ws[O_X  + (size_t)nb*96 + idx];
    ss[idx] = ws[O_S2 + (size_t)nb*96 + idx];
    sh[idx] = ws[O_H  + (size_t)nb*96 + idx];
  }
  __syncthreads();

  float a0[4],a1[4],a2[4],a3[4];
  {
    float gb0=ws[O_GB+j], gb1=ws[O_GB+96+j], gb2=ws[O_GB+192+j], gb3=ws[O_GB+288+j];
    #pragma unroll
    for (int i=0;i<4;i++){ a0[i]=gb0; a1[i]=gb1; a2[i]=gb2; a3[i]=gb3; }
  }
  // phase 1: frozen-input gate term  W_ihx @ x
  #pragma unroll 2
  for (int k=0;k<96;k++){
    float w0=WX[k*384+j], w1=WX[k*384+96+j], w2=WX[k*384+192+j], w3=WX[k*384+288+j];
    #pragma unroll
    for (int i=0;i<4;i++){
      float xv = sx[(g*4+i)*96+k];
      a0[i]=fmaf(w0,xv,a0[i]); a1[i]=fmaf(w1,xv,a1[i]);
      a2[i]=fmaf(w2,xv,a2[i]); a3[i]=fmaf(w3,xv,a3[i]);
    }
  }
  // phase 2: message (Wcomb@s2) + recurrent (Whh@rh), rh = (t==0 ? 0 : h)
  #pragma unroll 2
  for (int k=0;k<96;k++){
    float c0=WC[k*384+j], c1=WC[k*384+96+j], c2=WC[k*384+192+j], c3=WC[k*384+288+j];
    float h0=WH[k*384+j], h1=WH[k*384+96+j], h2=WH[k*384+192+j], h3=WH[k*384+288+j];
    #pragma unroll
    for (int i=0;i<4;i++){
      float sv = ss[(g*4+i)*96+k];
      float rv = sh[(g*4+i)*96+k] * hscale;
      a0[i]=fmaf(c0,sv,fmaf(h0,rv,a0[i]));
      a1[i]=fmaf(c1,sv,fmaf(h1,rv,a1[i]));
      a2[i]=fmaf(c2,sv,fmaf(h2,rv,a2[i]));
      a3[i]=fmaf(c3,sv,fmaf(h3,rv,a3[i]));
    }
  }
  float nh[4], ncv[4];
  #pragma unroll
  for (int i=0;i<4;i++){
    int n=n0+i;
    float ig=sigm(a0[i]), fg=sigm(a1[i]), gg=tanhf(a2[i]), og=sigm(a3[i]);
    float cv = c[(size_t)n*96+j];
    float nc = fg*cv + ig*gg;
    float nv = og*tanhf(nc);
    ncv[i]=nc; nh[i]=nv;
    lh[(g*4+i)*97 + j] = nv;
  }
  __syncthreads();
  #pragma unroll
  for (int i=0;i<4;i++){ int n=n0+i; c[(size_t)n*96+j]=ncv[i]; h[(size_t)n*96+j]=nh[i]; }

  // next-step A/B from fresh h (in LDS)
  const float* WA = ws + O_W0AT; const float* WB = ws + O_W0BT;
  float aa[4],ab[4];
  #pragma unroll
  for (int i=0;i<4;i++){ aa[i]=0.f; ab[i]=0.f; }
  #pragma unroll 2
  for (int k=0;k<96;k++){
    float wa=WA[k*96+j], wb=WB[k*96+j];
    #pragma unroll
    for (int i=0;i<4;i++){
      float hv = lh[(g*4+i)*97 + k];
      aa[i]=fmaf(wa,hv,aa[i]); ab[i]=fmaf(wb,hv,ab[i]);
    }
  }
  float* Aa=ws+O_A; float* Bb=ws+O_BV;
  float b0v = msgb[j];
  #pragma unroll
  for (int i=0;i<4;i++){ int n=n0+i; Aa[(size_t)n*96+j]=aa[i]; Bb[(size_t)n*96+j]=ab[i]+b0v; }

  // logits for this step
  if (j < 40){
    int ln = j/10, cls = j%10;
    int n = n0 + ln;
    float q0=outb[cls], q1=0.f, q2=0.f, q3=0.f;
    const float* hr = &lh[(g*4+ln)*97];
    #pragma unroll
    for (int k=0;k<96;k+=4){
      q0=fmaf(outW[cls*96+k  ],hr[k  ],q0); q1=fmaf(outW[cls*96+k+1],hr[k+1],q1);
      q2=fmaf(outW[cls*96+k+2],hr[k+2],q2); q3=fmaf(outW[cls*96+k+3],hr[k+3],q3);
    }
    float lg = (q0+q1)+(q2+q3);
    lgt[(g*4+ln)*10 + cls] = lg;
    out[165889 + ((size_t)t*NN + n)*10 + cls] = lg;
  }
  __syncthreads();
  if (j < 4){
    int n = n0 + j;
    const float* L = &lgt[(g*4+j)*10];
    float m = L[0]; int bi = 0;
    #pragma unroll
    for (int cc=1;cc<10;cc++){ if (L[cc] > m){ m=L[cc]; bi=cc; } }
    float se = 0.f;
    #pragma unroll
    for (int cc=0;cc<10;cc++) se += expf(L[cc]-m);
    int lab = labels[n];
    float lp = L[lab] - m - logf(se);
    atomicAdd(ws + O_LOSS, -lp);
    out[t*NN + n] = (float)bi;
  }
}

__global__ void k_final(float* ws, float* out){
  if (threadIdx.x == 0 && blockIdx.x == 0)
    out[165888] = ws[O_LOSS] / (float)(TT*NN);
}

extern "C" void kernel_launch(void* const* d_in, const int* in_sizes, int n_in,
                              void* d_out, int out_size, void* d_ws, size_t ws_size,
                              hipStream_t stream)
{
  (void)in_sizes; (void)n_in; (void)out_size; (void)ws_size;
  const int* q      = (const int*)d_in[0];
  const int* row    = (const int*)d_in[1];
  const int* col    = (const int*)d_in[2];
  const int* labels = (const int*)d_in[3];
  const int* dst    = (const int*)d_in[5];
  const float* demb  = (const float*)d_in[6];
  const float* remb  = (const float*)d_in[7];
  const float* cemb  = (const float*)d_in[8];
  const float* inW0  = (const float*)d_in[9];
  const float* inW   = (const float*)d_in[10];
  const float* inb   = (const float*)d_in[11];
  const float* msgW0 = (const float*)d_in[12];
  const float* msgW  = (const float*)d_in[13];
  const float* msgb  = (const float*)d_in[14];
  const float* Wih   = (const float*)d_in[15];
  const float* Whh   = (const float*)d_in[16];
  const float* outW  = (const float*)d_in[17];
  const float* outb  = (const float*)d_in[18];

  float* ws  = (float*)d_ws;
  float* out = (float*)d_out;

  hipLaunchKernelGGL(k_convert, dim3(487), dim3(256), 0, stream,
                     ws, msgW0, Whh, Wih, inW0, inW);
  hipLaunchKernelGGL(k_wfrag, dim3(27), dim3(256), 0, stream, ws, msgW);
  hipLaunchKernelGGL(k_wcomb, dim3(144), dim3(256), 0, stream, ws, Wih, msgW, msgb);
  hipLaunchKernelGGL(k_input, dim3(648), dim3(192), 0, stream,
                     ws, q, row, col, demb, remb, cemb, inb, msgb);
  for (int t=0; t<TT; ++t){
    hipLaunchKernelGGL(k_edge, dim3(EE/80), dim3(320), 0, stream, ws, dst, msgb);
    hipLaunchKernelGGL(k_lstm, dim3(1296), dim3(192), 0, stream,
                       ws, labels, msgb, outW, outb, out, t);
  }
  hipLaunchKernelGGL(k_final, dim3(1), dim3(64), 0, stream, ws, out);
}